// Round 5
// baseline (460.599 us; speedup 1.0000x reference)
//
#include <hip/hip_runtime.h>
#include <hip/hip_cooperative_groups.h>
#include <math.h>

namespace cg = cooperative_groups;

// Problem dims
#define B_   512
#define F_   1024
#define H1_  512
#define H2_  256
#define OUT_ 128
#define KD_  5
#define NT_  640
#define ZK_  384   // H2_ + OUT_

typedef short bf16x8 __attribute__((ext_vector_type(8)));
typedef float f32x16 __attribute__((ext_vector_type(16)));

__device__ __forceinline__ float lrelu(float v) { return v >= 0.f ? v : 0.2f * v; }

// fp32 -> bf16 round-to-nearest-even
__device__ __forceinline__ unsigned f2bf(float f) {
    unsigned u = __float_as_uint(f);
    return (u + 0x7fffu + ((u >> 16) & 1u)) >> 16;
}
__device__ __forceinline__ unsigned pack2bf(float a, float b) {
    return f2bf(a) | (f2bf(b) << 16);
}

// pack unit counts
#define NXB 256
#define NW1 512
#define NW2 128
#define NTT 160
#define NW3 48
#define PACK_UNITS (NXB + NW1 + NW2 + NTT + NW3)   // 1104

// ---------------------------------------------------------------------------
// One 32x32 transpose+bf16-pack unit (from the round-4 pack kernel, which
// passed). Tl is the block's 32x33 LDS tile.
// ---------------------------------------------------------------------------
__device__ __forceinline__
void pack_transpose_unit(int u, int t,
                         const float* __restrict__ W1, const float* __restrict__ W2,
                         const float* __restrict__ T,  const float* __restrict__ W3,
                         unsigned short* __restrict__ W1t, unsigned short* __restrict__ W2t,
                         unsigned short* __restrict__ Tt,  unsigned short* __restrict__ W3t,
                         float (*Tl)[33])
{
    const float* src; unsigned short* dst; int R, C, tile;
    int b = u;
    if (b < NW1)               { src = W1; dst = W1t; R = 1024; C = 512; tile = b; }
    else if ((b -= NW1) < NW2) { src = W2; dst = W2t; R = 512;  C = 256; tile = b; }
    else if ((b -= NW2) < NTT) { src = T;  dst = Tt;  R = 256;  C = 640; tile = b; }
    else                       { b -= NTT;  src = W3; dst = W3t; R = 384; C = 128; tile = b; }
    const int tpc = C / 32;
    const int tr = tile / tpc, tc = tile % tpc;
    const int col = t & 31, rr = t >> 5;
    #pragma unroll
    for (int p = 0; p < 4; ++p)
        Tl[rr + 8 * p][col] = src[(size_t)(tr * 32 + rr + 8 * p) * C + tc * 32 + col];
    __syncthreads();
    const int orow = t >> 3, up = t & 7;
    unsigned* d = (unsigned*)(dst + (size_t)(tc * 32 + orow) * R + tr * 32);
    d[up]     = pack2bf(Tl[2 * up][orow],      Tl[2 * up + 1][orow]);
    d[up + 8] = pack2bf(Tl[2 * up + 16][orow], Tl[2 * up + 17][orow]);
    __syncthreads();   // Tl reused next loop iteration
}

// ---------------------------------------------------------------------------
// Barrier-free MFMA 32x32-tile GEMM step (4 waves, K split across waves,
// LDS tree reduction + fused epilogue). Same math as the round-4 kernel
// (verified, absmax 5.9e-3). Red = 4096-float LDS scratch.
// ---------------------------------------------------------------------------
template<int KSLICE, bool RELU, bool HAS_BIAS, bool BF16_OUT, bool CONCAT_A>
__device__ __forceinline__
void gemm_tile(const unsigned short* __restrict__ Ab, const float* __restrict__ obf,
               const unsigned short* __restrict__ Bt, const float* __restrict__ bias,
               void* __restrict__ Cout, int N, int LDA, int LDB,
               int m0, int n0, float* Red, int tid)
{
    const int wav  = tid >> 6;
    const int lane = tid & 63;
    const int half = lane >> 5;
    const int mn   = lane & 31;
    const int kw   = wav * KSLICE;

    f32x16 acc;
    #pragma unroll
    for (int i = 0; i < 16; ++i) acc[i] = 0.f;

    const unsigned short* arow = Ab + (size_t)(m0 + mn) * LDA;
    const unsigned short* brow = Bt + (size_t)(n0 + mn) * LDB;

    #pragma unroll
    for (int s = 0; s < KSLICE / 16; ++s) {
        const int k = kw + 16 * s + 8 * half;
        bf16x8 af, bf;
        if (CONCAT_A) {
            if (k < H2_) {
                af = *(const bf16x8*)&Ab[(size_t)(m0 + mn) * H2_ + k];
            } else {
                const float* pa = obf + (size_t)(m0 + mn) * OUT_ + (k - H2_);
                union { unsigned u[4]; bf16x8 v; } cv;
                #pragma unroll
                for (int jj = 0; jj < 4; ++jj)
                    cv.u[jj] = pack2bf(pa[2 * jj], pa[2 * jj + 1]);
                af = cv.v;
            }
        } else {
            af = *(const bf16x8*)&arow[k];
        }
        bf = *(const bf16x8*)&brow[k];
        acc = __builtin_amdgcn_mfma_f32_32x32x16_bf16(af, bf, acc, 0, 0, 0);
    }

    // C/D layout (verified): col = lane&31, row = (reg&3) + 8*(reg>>2) + 4*(lane>>5)
    #pragma unroll
    for (int r = 0; r < 16; ++r) {
        const int row = (r & 3) + 8 * (r >> 2) + 4 * half;
        Red[wav * 1024 + row * 32 + mn] = acc[r];
    }
    __syncthreads();

    {
        const int e0 = tid * 4, row = e0 >> 5, col = e0 & 31;
        float v[4];
        #pragma unroll
        for (int q = 0; q < 4; ++q) {
            float u = Red[e0 + q] + Red[1024 + e0 + q] + Red[2048 + e0 + q] + Red[3072 + e0 + q];
            if (HAS_BIAS) u += bias[n0 + col + q];
            if (RELU) u = lrelu(u);
            v[q] = u;
        }
        if (BF16_OUT) {
            uint2 o;
            o.x = pack2bf(v[0], v[1]); o.y = pack2bf(v[2], v[3]);
            *(uint2*)((unsigned short*)Cout + (size_t)(m0 + row) * N + n0 + col) = o;
        } else {
            *(float4*)((float*)Cout + (size_t)(m0 + row) * N + n0 + col) =
                make_float4(v[0], v[1], v[2], v[3]);
        }
    }
    __syncthreads();   // Red reused by next tile / stage
}

// ---------------------------------------------------------------------------
// THE fused kernel: 256 blocks x 256 threads, cooperative, 7 stages.
// ---------------------------------------------------------------------------
__global__ __launch_bounds__(256, 1)
void fused_all(const float* __restrict__ x,  const float* __restrict__ W1,
               const float* __restrict__ b1, const float* __restrict__ W2,
               const float* __restrict__ b2, const float* __restrict__ T,
               const float* __restrict__ W3, const float* __restrict__ b3,
               const float* __restrict__ W4, const float* __restrict__ b4,
               float* __restrict__ out, char* __restrict__ ws)
{
    __shared__ __align__(16) char smem[16384];
    float* Red = (float*)smem;                 // 4096 f32 (gemm reduction)
    float* Lsh = (float*)smem;                 // 512*8 f32 (disc stage)
    float (*Tl)[33] = (float(*)[33])smem;      // 32x33 (pack stage)

    // workspace layout (bytes, all 16B aligned)
    float*          Mt  = (float*)(ws + 0);                  // 640*512*4
    float*          ob  = (float*)(ws + 1310720);            // 512*128*4
    float*          z3  = (float*)(ws + 1572864);            // 512*128*4
    unsigned short* xb  = (unsigned short*)(ws + 1835008);   // 512*1024*2
    unsigned short* W1t = (unsigned short*)(ws + 2883584);   // 512*1024*2
    unsigned short* W2t = (unsigned short*)(ws + 3932160);   // 256*512*2
    unsigned short* Tt  = (unsigned short*)(ws + 4194304);   // 640*256*2
    unsigned short* W3t = (unsigned short*)(ws + 4521984);   // 128*384*2
    unsigned short* h1b = (unsigned short*)(ws + 4620288);   // 512*512*2
    unsigned short* h2b = (unsigned short*)(ws + 5144576);   // 512*256*2

    const int bid = blockIdx.x;
    const int t   = threadIdx.x;
    cg::grid_group grid = cg::this_grid();

    // ---- Stage 1: pack all bf16 operands (x convert + 4 weight transposes)
    for (int u = bid; u < PACK_UNITS; u += 256) {
        if (u < NXB) {
            const int base = u * 2048 + t * 8;
            const float4 a = *(const float4*)(x + base);
            const float4 c = *(const float4*)(x + base + 4);
            uint4 o;
            o.x = pack2bf(a.x, a.y); o.y = pack2bf(a.z, a.w);
            o.z = pack2bf(c.x, c.y); o.w = pack2bf(c.z, c.w);
            *(uint4*)(xb + base) = o;
        } else {
            pack_transpose_unit(u - NXB, t, W1, W2, T, W3, W1t, W2t, Tt, W3t, Tl);
        }
    }
    __threadfence(); grid.sync();

    // ---- Stage 2: h1 = lrelu(x @ W1 + b1)  (512x512, K=1024) -> bf16
    gemm_tile<256, true, true, true, false>(xb, nullptr, W1t, b1, h1b,
        H1_, F_, F_, (bid >> 4) * 32, (bid & 15) * 32, Red, t);
    __threadfence(); grid.sync();

    // ---- Stage 3: h2 = lrelu(h1 @ W2 + b2) (512x256, K=512) -> bf16
    if (bid < 128)
        gemm_tile<128, true, true, true, false>(h1b, nullptr, W2t, b2, h2b,
            H2_, H1_, H1_, (bid >> 3) * 32, (bid & 7) * 32, Red, t);
    __threadfence(); grid.sync();

    // ---- Stage 4: Mt = T^T @ h2^T  (640x512, K=256) -> fp32 (Mt direct)
    for (int u = bid; u < 320; u += 256)
        gemm_tile<64, false, false, false, false>(Tt, nullptr, h2b, nullptr, Mt,
            B_, H2_, H2_, (u / 16) * 32, (u % 16) * 32, Red, t);
    __threadfence(); grid.sync();

    // ---- Stage 5: minibatch discrimination -> ob[j][o]
    {
        const int o  = bid >> 1;
        const int jh = bid & 1;
        const int j  = jh * 256 + t;
        const float* base = Mt + (size_t)o * 5 * 512;
        #pragma unroll
        for (int k = 0; k < KD_; ++k) {
            Lsh[t * 8 + k]         = base[k * 512 + t];
            Lsh[(t + 256) * 8 + k] = base[k * 512 + 256 + t];
        }
        const float mj0 = base[0 * 512 + j], mj1 = base[1 * 512 + j],
                    mj2 = base[2 * 512 + j], mj3 = base[3 * 512 + j],
                    mj4 = base[4 * 512 + j];
        __syncthreads();
        float acc0 = 0.f, acc1 = 0.f;
        #pragma unroll 4
        for (int i = 0; i < 512; i += 2) {
            const float4 a = *(const float4*)&Lsh[i * 8];
            const float n0 = fabsf(a.x - mj0) + fabsf(a.y - mj1) + fabsf(a.z - mj2)
                           + fabsf(a.w - mj3) + fabsf(Lsh[i * 8 + 4] - mj4);
            acc0 += __expf(-n0);
            const float4 b = *(const float4*)&Lsh[(i + 1) * 8];
            const float n1 = fabsf(b.x - mj0) + fabsf(b.y - mj1) + fabsf(b.z - mj2)
                           + fabsf(b.w - mj3) + fabsf(Lsh[(i + 1) * 8 + 4] - mj4);
            acc1 += __expf(-n1);
        }
        ob[(size_t)j * OUT_ + o] = acc0 + acc1 - 1.f;   // exact self term
        __syncthreads();   // Lsh reused as Red next stage
    }
    __threadfence(); grid.sync();

    // ---- Stage 6: z3 = lrelu(concat([h2, ob]) @ W3 + b3) (512x128, K=384)
    if (bid < 64)
        gemm_tile<96, true, true, false, true>(h2b, ob, W3t, b3, z3,
            OUT_, H2_, ZK_, (bid >> 2) * 32, (bid & 3) * 32, Red, t);
    __threadfence(); grid.sync();

    // ---- Stage 7: out = z3 @ W4 + b4
    if (bid < 8) {
        const int row = bid * 64 + (t >> 2);
        const int q = t & 3;
        const float4* z = (const float4*)(z3 + (size_t)row * OUT_ + q * 32);
        const float4* w = (const float4*)(W4 + q * 32);
        float acc = 0.f;
        #pragma unroll
        for (int k = 0; k < 8; ++k) {
            const float4 a = z[k], b = w[k];
            acc += a.x * b.x + a.y * b.y + a.z * b.z + a.w * b.w;
        }
        acc += __shfl_down(acc, 2, 4);
        acc += __shfl_down(acc, 1, 4);
        if (q == 0) out[row] = acc + b4[0];
    }
}

extern "C" void kernel_launch(void* const* d_in, const int* in_sizes, int n_in,
                              void* d_out, int out_size, void* d_ws, size_t ws_size,
                              hipStream_t stream) {
    const float* x  = (const float*)d_in[0];
    const float* W1 = (const float*)d_in[1];
    const float* b1 = (const float*)d_in[2];
    const float* W2 = (const float*)d_in[3];
    const float* b2 = (const float*)d_in[4];
    const float* T  = (const float*)d_in[5];
    const float* W3 = (const float*)d_in[6];
    const float* b3 = (const float*)d_in[7];
    const float* W4 = (const float*)d_in[8];
    const float* b4 = (const float*)d_in[9];
    float* out = (float*)d_out;
    char* ws = (char*)d_ws;

    void* args[] = { (void*)&x, (void*)&W1, (void*)&b1, (void*)&W2, (void*)&b2,
                     (void*)&T, (void*)&W3, (void*)&b3, (void*)&W4, (void*)&b4,
                     (void*)&out, (void*)&ws };
    hipLaunchCooperativeKernel((void*)fused_all, dim3(256), dim3(256),
                               args, 0, stream);
}

// Round 6
// 110.577 us; speedup vs baseline: 4.1654x; 4.1654x over previous
//
#include <hip/hip_runtime.h>
#include <math.h>

// Problem dims
#define B_   512
#define F_   1024
#define H1_  512
#define H2_  256
#define OUT_ 128
#define KD_  5
#define NT_  640
#define ZK_  384   // H2_ + OUT_

typedef short bf16x8 __attribute__((ext_vector_type(8)));
typedef float f32x16 __attribute__((ext_vector_type(16)));

__device__ __forceinline__ float lrelu(float v) { return v >= 0.f ? v : 0.2f * v; }

// fp32 -> bf16 round-to-nearest-even
__device__ __forceinline__ unsigned f2bf(float f) {
    unsigned u = __float_as_uint(f);
    return (u + 0x7fffu + ((u >> 16) & 1u)) >> 16;
}
__device__ __forceinline__ unsigned pack2bf(float a, float b) {
    return f2bf(a) | (f2bf(b) << 16);
}

// ---------------------------------------------------------------------------
// MFMA fragment loaders (A/B lane layout: idx = lane&31, k = (lane>>5)*8 + j,
// j = 0..7 contiguous). All verified in rounds 3-4 (absmax 5.9e-3).
// ---------------------------------------------------------------------------
__device__ __forceinline__ bf16x8 frag_bf16row(const unsigned short* p, int idx, int ld, int k) {
    return *(const bf16x8*)(p + (size_t)idx * ld + k);
}
__device__ __forceinline__ bf16x8 frag_f32row(const float* p, int idx, int ld, int k) {
    const float4 a = *(const float4*)(p + (size_t)idx * ld + k);
    const float4 b = *(const float4*)(p + (size_t)idx * ld + k + 4);
    union { unsigned u[4]; bf16x8 v; } cv;
    cv.u[0] = pack2bf(a.x, a.y); cv.u[1] = pack2bf(a.z, a.w);
    cv.u[2] = pack2bf(b.x, b.y); cv.u[3] = pack2bf(b.z, b.w);
    return cv.v;
}
// column gather from fp32 [K][ld] matrix: element j = p[(k+j)*ld + idx]
__device__ __forceinline__ bf16x8 frag_f32col(const float* p, int idx, int ld, int k) {
    union { unsigned u[4]; bf16x8 v; } cv;
    #pragma unroll
    for (int jj = 0; jj < 4; ++jj)
        cv.u[jj] = pack2bf(p[(size_t)(k + 2 * jj) * ld + idx],
                           p[(size_t)(k + 2 * jj + 1) * ld + idx]);
    return cv.v;
}
// concat([h2b bf16 (ld 256), obA+obB fp32 (ld 128)]) row, K=384
__device__ __forceinline__ bf16x8 frag_concat(const unsigned short* h2b,
                                              const float* obA, const float* obB,
                                              int idx, int k) {
    if (k < H2_) return frag_bf16row(h2b, idx, H2_, k);
    const float* pa = obA + (size_t)idx * OUT_ + (k - H2_);
    const float* pb = obB + (size_t)idx * OUT_ + (k - H2_);
    union { unsigned u[4]; bf16x8 v; } cv;
    #pragma unroll
    for (int jj = 0; jj < 4; ++jj)
        cv.u[jj] = pack2bf(pa[2 * jj] + pb[2 * jj], pa[2 * jj + 1] + pb[2 * jj + 1]);
    return cv.v;
}

// operand modes
#define M_BF16ROW 0
#define M_F32ROW  1
#define M_F32COL  2

// ---------------------------------------------------------------------------
// Barrier-free MFMA GEMM, one 32x32 tile per block, K split across WAVES
// waves (no barriers/LDS in the K-loop; single LDS reduction + epilogue).
// ---------------------------------------------------------------------------
template<int WAVES, int KSLICE, int AMODE, int BMODE,
         bool RELU, bool HAS_BIAS, bool BF16_OUT>
__global__ __launch_bounds__(WAVES * 64)
void gemm_k(const void* __restrict__ Ap, const void* __restrict__ Bp,
            const float* __restrict__ bias, void* __restrict__ Cout,
            int M, int N, int LDA, int LDB)
{
    __shared__ float Red[WAVES * 1024];
    const int tid  = threadIdx.x;
    const int wav  = tid >> 6;
    const int lane = tid & 63;
    const int half = lane >> 5;
    const int mn   = lane & 31;
    const int m0   = blockIdx.y * 32;
    const int n0   = blockIdx.x * 32;

    f32x16 acc;
    #pragma unroll
    for (int i = 0; i < 16; ++i) acc[i] = 0.f;

    #pragma unroll
    for (int s = 0; s < KSLICE / 16; ++s) {
        const int k = wav * KSLICE + 16 * s + 8 * half;
        bf16x8 af, bf;
        if (AMODE == M_BF16ROW)      af = frag_bf16row((const unsigned short*)Ap, m0 + mn, LDA, k);
        else if (AMODE == M_F32ROW)  af = frag_f32row((const float*)Ap, m0 + mn, LDA, k);
        else                         af = frag_f32col((const float*)Ap, m0 + mn, LDA, k);
        if (BMODE == M_BF16ROW)      bf = frag_bf16row((const unsigned short*)Bp, n0 + mn, LDB, k);
        else                         bf = frag_f32col((const float*)Bp, n0 + mn, LDB, k);
        acc = __builtin_amdgcn_mfma_f32_32x32x16_bf16(af, bf, acc, 0, 0, 0);
    }

    // C/D layout (verified): col = lane&31, row = (reg&3) + 8*(reg>>2) + 4*(lane>>5)
    #pragma unroll
    for (int r = 0; r < 16; ++r) {
        const int row = (r & 3) + 8 * (r >> 2) + 4 * half;
        Red[wav * 1024 + row * 32 + mn] = acc[r];
    }
    __syncthreads();

    if (tid < 256) {
        const int e0 = tid * 4, row = e0 >> 5, col = e0 & 31;
        float v[4];
        #pragma unroll
        for (int q = 0; q < 4; ++q) {
            float u = 0.f;
            #pragma unroll
            for (int w = 0; w < WAVES; ++w) u += Red[w * 1024 + e0 + q];
            if (HAS_BIAS) u += bias[n0 + col + q];
            if (RELU) u = lrelu(u);
            v[q] = u;
        }
        if (BF16_OUT) {
            uint2 o;
            o.x = pack2bf(v[0], v[1]); o.y = pack2bf(v[2], v[3]);
            *(uint2*)((unsigned short*)Cout + (size_t)(m0 + row) * N + n0 + col) = o;
        } else {
            *(float4*)((float*)Cout + (size_t)(m0 + row) * N + n0 + col) =
                make_float4(v[0], v[1], v[2], v[3]);
        }
    }
}

// ---------------------------------------------------------------------------
// Minibatch discrimination (verified round 4): Mt fp32 [640][512],
// block = (o, j-quarter, i-half): 1024 blocks x 128 threads.
// obH[ih][j][o] = sum_{i in half} exp(-L1) - (self ? 1 : 0)
// ---------------------------------------------------------------------------
__global__ __launch_bounds__(128)
void disc_kernel(const float* __restrict__ Mt, float* __restrict__ obH)
{
    const int o  = blockIdx.x >> 3;
    const int jq = (blockIdx.x >> 1) & 3;
    const int ih = blockIdx.x & 1;
    const int t  = threadIdx.x;
    const int j  = jq * 128 + t;
    const int i0 = ih * 256;
    __shared__ float L[256 * 8];
    const float* base = Mt + (size_t)o * 5 * 512;
    #pragma unroll
    for (int k = 0; k < KD_; ++k) {
        L[t * 8 + k]         = base[k * 512 + i0 + t];
        L[(t + 128) * 8 + k] = base[k * 512 + i0 + t + 128];
    }
    const float mj0 = base[0 * 512 + j], mj1 = base[1 * 512 + j],
                mj2 = base[2 * 512 + j], mj3 = base[3 * 512 + j],
                mj4 = base[4 * 512 + j];
    __syncthreads();

    float acc0 = 0.f, acc1 = 0.f;
    #pragma unroll 4
    for (int i = 0; i < 256; i += 2) {
        {
            const float4 a = *(const float4*)&L[i * 8];
            const float n = fabsf(a.x - mj0) + fabsf(a.y - mj1) + fabsf(a.z - mj2)
                          + fabsf(a.w - mj3) + fabsf(L[i * 8 + 4] - mj4);
            acc0 += __expf(-n);
        }
        {
            const float4 a = *(const float4*)&L[(i + 1) * 8];
            const float n = fabsf(a.x - mj0) + fabsf(a.y - mj1) + fabsf(a.z - mj2)
                          + fabsf(a.w - mj3) + fabsf(L[(i + 1) * 8 + 4] - mj4);
            acc1 += __expf(-n);
        }
    }
    const float self = ((j >> 8) == ih) ? 1.f : 0.f;
    obH[(size_t)ih * B_ * OUT_ + (size_t)j * OUT_ + o] = acc0 + acc1 - self;
}

// ---------------------------------------------------------------------------
// Fused GEMM3 + final dot: 16 blocks x 256 threads. Block = 32-row strip.
// Wave w computes col-tile n0 = w*32 over full K=384 (concat A, W3 col
// gather B). Epilogue: bias+lrelu into Red[32][128], then rotated LDS dot
// with W4 -> out.
// ---------------------------------------------------------------------------
__global__ __launch_bounds__(256)
void gemm3_dot(const unsigned short* __restrict__ h2b,
               const float* __restrict__ obA, const float* __restrict__ obB,
               const float* __restrict__ W3, const float* __restrict__ b3,
               const float* __restrict__ W4, const float* __restrict__ b4,
               float* __restrict__ out)
{
    __shared__ float Red[32 * 128];
    const int tid  = threadIdx.x;
    const int w    = tid >> 6;
    const int lane = tid & 63;
    const int half = lane >> 5;
    const int mn   = lane & 31;
    const int m0   = blockIdx.x * 32;
    const int n0   = w * 32;

    f32x16 acc;
    #pragma unroll
    for (int i = 0; i < 16; ++i) acc[i] = 0.f;

    #pragma unroll
    for (int s = 0; s < ZK_ / 16; ++s) {
        const int k = 16 * s + 8 * half;
        const bf16x8 af = frag_concat(h2b, obA, obB, m0 + mn, k);
        const bf16x8 bf = frag_f32col(W3, n0 + mn, OUT_, k);
        acc = __builtin_amdgcn_mfma_f32_32x32x16_bf16(af, bf, acc, 0, 0, 0);
    }

    #pragma unroll
    for (int r = 0; r < 16; ++r) {
        const int row = (r & 3) + 8 * (r >> 2) + 4 * half;
        const int col = n0 + mn;
        Red[row * 128 + col] = lrelu(acc[r] + b3[col]);
    }
    __syncthreads();

    if (tid < 128) {
        const int row = tid >> 2, q = tid & 3;
        float a = 0.f;
        #pragma unroll
        for (int cc0 = 0; cc0 < 32; ++cc0) {
            const int cc = (cc0 + tid) & 31;       // rotation: 2-way LDS aliasing (free)
            a += Red[row * 128 + q * 32 + cc] * W4[q * 32 + cc];
        }
        a += __shfl_down(a, 2, 4);
        a += __shfl_down(a, 1, 4);
        if (q == 0) out[m0 + row] = a + b4[0];
    }
}

extern "C" void kernel_launch(void* const* d_in, const int* in_sizes, int n_in,
                              void* d_out, int out_size, void* d_ws, size_t ws_size,
                              hipStream_t stream) {
    const float* x  = (const float*)d_in[0];   // (512, 1024)
    const float* W1 = (const float*)d_in[1];   // (1024, 512)
    const float* b1 = (const float*)d_in[2];   // (512,)
    const float* W2 = (const float*)d_in[3];   // (512, 256)
    const float* b2 = (const float*)d_in[4];   // (256,)
    const float* T  = (const float*)d_in[5];   // (256, 640) flat
    const float* W3 = (const float*)d_in[6];   // (384, 128)
    const float* b3 = (const float*)d_in[7];   // (128,)
    const float* W4 = (const float*)d_in[8];   // (128, 1)
    const float* b4 = (const float*)d_in[9];   // (1,)
    float* out = (float*)d_out;                // (512,)

    char* ws = (char*)d_ws;
    float*          Mt  = (float*)(ws + 0);                  // 640*512*4   = 1310720
    float*          obH = (float*)(ws + 1310720);            // 2*512*128*4 =  524288
    unsigned short* h1b = (unsigned short*)(ws + 1835008);   // 512*512*2   =  524288
    unsigned short* h2b = (unsigned short*)(ws + 2359296);   // 512*256*2   =  262144
    // total 2,621,440 bytes

    // 1) h1 = lrelu(x @ W1 + b1)  (512x512, K=1024) -> bf16
    //    A: fp32 rows of x ; B: fp32 column gather of W1
    gemm_k<8, 128, M_F32ROW, M_F32COL, true, true, true>
        <<<dim3(H1_ / 32, B_ / 32), 512, 0, stream>>>(
        x, W1, b1, h1b, B_, H1_, F_, H1_);

    // 2) h2 = lrelu(h1 @ W2 + b2) (512x256, K=512) -> bf16
    gemm_k<8, 64, M_BF16ROW, M_F32COL, true, true, true>
        <<<dim3(H2_ / 32, B_ / 32), 512, 0, stream>>>(
        h1b, W2, b2, h2b, B_, H2_, H1_, H2_);

    // 3) Mt = (h2 @ T)^T directly: A = T columns (fp32 gather, ld 640),
    //    B = h2b rows (bf16) -> Mt fp32 [640][512]
    gemm_k<4, 64, M_F32COL, M_BF16ROW, false, false, false>
        <<<dim3(B_ / 32, NT_ / 32), 256, 0, stream>>>(
        T, h2b, nullptr, Mt, NT_, B_, NT_, H2_);

    // 4) minibatch discrimination -> obH (two i-half partials)
    disc_kernel<<<1024, 128, 0, stream>>>(Mt, obH);

    // 5) out = (lrelu(concat([h2, ob]) @ W3 + b3)) @ W4 + b4
    gemm3_dot<<<B_ / 32, 256, 0, stream>>>(
        h2b, obH, obH + B_ * OUT_, W3, b3, W4, b4, out);
}